// Round 8
// baseline (771.921 us; speedup 1.0000x reference)
//
#include <hip/hip_runtime.h>

// LSTM scan: S=2048, B=4096, IN=1, H=10.
// Round-8 vs round-7 (FAILED, absmax 0.40):
//  Root cause: DPP direction. row_ror:n reads from lane (i-n)&15 (same
//  direction family as row_shr, which implements __shfl_up / rocPRIM scans),
//  NOT (i+n). Round-7 pre-rotated weights as W[q][(q+r)&15]; the rotation
//  chain delivers h_{(q-r)&15}. Fix (one line): pre-rotate the other way,
//  wr_g[r] = W_g[q][(q+16-r)&15]. Forward ror:1 chain (r=1..8) pairs
//  h_{(q-R)} with wr[R]; backward ror:15 chain (lane reads (i+1)) pairs
//  h_{(q+r')} with wr[16-r'] for r'=1..7 (RSTEP_B(15..9), unchanged).
//  Everything else identical to round 7:
//   - NO LDS: h one register/lane; matvec via 15 DPP rotations
//   - fc dot via 4-step DPP ror butterfly (direction-agnostic, was correct)
//   - in-loop asm volatile "+v" pins on all weight regs
//   - depth-4 x prefetch
//  Gates: LDS_Block_Size==0, VGPR>=96. Predict 250-350us, VALUBusy 75-90%.

#define SEQ   2048
#define BATCH 4096

__device__ __forceinline__ float rcpf(float v) { return __builtin_amdgcn_rcpf(v); }
__device__ __forceinline__ float ex2(float v)  { return __builtin_amdgcn_exp2f(v); }

// DPP move: row_ror:n ctrl = 0x120+n. Full row/bank masks, bound_ctrl=1.
template<int CTRL>
__device__ __forceinline__ float dppf(float x) {
    return __int_as_float(__builtin_amdgcn_update_dpp(
        0, __float_as_int(x), CTRL, 0xF, 0xF, true));
}
#define ROR1  0x121   /* lane i <- lane (i-1)&15  */
#define ROR2  0x122
#define ROR4  0x124
#define ROR8  0x128
#define ROL1  0x12F   /* row_ror:15: lane i <- lane (i+1)&15 */

__global__ __launch_bounds__(256, 1) void lstm_scan_kernel(
    const float* __restrict__ x,     // [S, B]
    const float* __restrict__ w_ih,  // [40, 1]
    const float* __restrict__ w_hh,  // [40, 10]
    const float* __restrict__ b_ih,  // [40]
    const float* __restrict__ b_hh,  // [40]
    const float* __restrict__ fc_w,  // [10]
    const float* __restrict__ fc_b,  // [1]
    float* __restrict__ out)         // [S, B]
{
    const int tid = threadIdx.x;
    const int grp = tid >> 4;        // 16-lane group = one batch element
    const int q   = tid & 15;        // lane within group = hidden unit j
    const int b   = (blockIdx.x << 4) + grp;

    const float L2E = 1.44269504088896f;
    const int  qs = (q < 10) ? q : 0;          // safe row index
    const float mq = (q < 10) ? 1.0f : 0.0f;   // zero-pad mask

    // Pre-rotated weights: wr_g[r] = scale_g * W_g[q][(q+16-r)&15], 0-padded.
    // (row_ror:1 applied R times delivers h_{(q-R)&15} -> pair with wr[R].)
    // Gate rows: i=q, f=10+q, g=20+q (tanh, scale -2L2E), o=30+q.
    float wr0[16], wr1[16], wr2[16], wr3[16];
#pragma unroll
    for (int r = 0; r < 16; ++r) {
        const int k  = (q + 16 - r) & 15;      // <-- round-8 fix (was (q+r)&15)
        const int ks = (k < 10) ? k : 0;
        const float m = (q < 10 && k < 10) ? 1.0f : 0.0f;
        wr0[r] = (-L2E)        * m * w_hh[(     qs) * 10 + ks];
        wr1[r] = (-L2E)        * m * w_hh[(10 + qs) * 10 + ks];
        wr2[r] = (-2.0f * L2E) * m * w_hh[(20 + qs) * 10 + ks];
        wr3[r] = (-L2E)        * m * w_hh[(30 + qs) * 10 + ks];
    }
    float wi0 = (-L2E)        * mq * w_ih[qs];
    float wi1 = (-L2E)        * mq * w_ih[10 + qs];
    float wi2 = (-2.0f * L2E) * mq * w_ih[20 + qs];
    float wi3 = (-L2E)        * mq * w_ih[30 + qs];
    float bi0 = (-L2E)        * mq * (b_ih[qs]      + b_hh[qs]);
    float bi1 = (-L2E)        * mq * (b_ih[10 + qs] + b_hh[10 + qs]);
    float bi2 = (-2.0f * L2E) * mq * (b_ih[20 + qs] + b_hh[20 + qs]);
    float bi3 = (-L2E)        * mq * (b_ih[30 + qs] + b_hh[30 + qs]);
    float fcj = mq * fc_w[qs];
    float fb  = fc_b[0];

    float c = 0.0f, h = 0.0f;   // lanes 10..15: all-zero weights => h stays 0

    // depth-4 x prefetch
    size_t ix = (size_t)b;
    float x0 = x[ix];
    float x1 = x[ix + (size_t)BATCH];
    float x2 = x[ix + 2 * (size_t)BATCH];
    float x3 = x[ix + 3 * (size_t)BATCH];

#define RSTEP_F(R)                                                            \
    hf = dppf<ROR1>(hf);                                                      \
    a0 = __builtin_fmaf(wr0[R], hf, a0);                                      \
    a1 = __builtin_fmaf(wr1[R], hf, a1);                                      \
    a2 = __builtin_fmaf(wr2[R], hf, a2);                                      \
    a3 = __builtin_fmaf(wr3[R], hf, a3);

#define RSTEP_B(R)                                                            \
    hb = dppf<ROL1>(hb);                                                      \
    p0 = __builtin_fmaf(wr0[R], hb, p0);                                      \
    p1 = __builtin_fmaf(wr1[R], hb, p1);                                      \
    p2 = __builtin_fmaf(wr2[R], hb, p2);                                      \
    p3 = __builtin_fmaf(wr3[R], hb, p3);

#define BODY(XV, IDX)                                                         \
    {                                                                         \
        const float xv = (XV);                                                \
        float a0 = __builtin_fmaf(wi0, xv, bi0);                              \
        float a1 = __builtin_fmaf(wi1, xv, bi1);                              \
        float a2 = __builtin_fmaf(wi2, xv, bi2);                              \
        float a3 = __builtin_fmaf(wi3, xv, bi3);                              \
        a0 = __builtin_fmaf(wr0[0], h, a0);                                   \
        a1 = __builtin_fmaf(wr1[0], h, a1);                                   \
        a2 = __builtin_fmaf(wr2[0], h, a2);                                   \
        a3 = __builtin_fmaf(wr3[0], h, a3);                                   \
        float p0 = 0.0f, p1 = 0.0f, p2 = 0.0f, p3 = 0.0f;                     \
        float hf = h, hb = h;                                                 \
        RSTEP_F(1) RSTEP_F(2) RSTEP_F(3) RSTEP_F(4)                           \
        RSTEP_F(5) RSTEP_F(6) RSTEP_F(7) RSTEP_F(8)                           \
        RSTEP_B(15) RSTEP_B(14) RSTEP_B(13) RSTEP_B(12)                       \
        RSTEP_B(11) RSTEP_B(10) RSTEP_B(9)                                    \
        const float g0 = a0 + p0;                                             \
        const float g1 = a1 + p1;                                             \
        const float g2 = a2 + p2;                                             \
        const float g3 = a3 + p3;                                             \
        const float e0 = ex2(g0) + 1.0f;                                      \
        const float e1 = ex2(g1) + 1.0f;                                      \
        const float e2 = ex2(g2) + 1.0f;                                      \
        const float e3 = ex2(g3) + 1.0f;                                      \
        const float iv = rcpf(e0);                                            \
        const float fv = rcpf(e1);                                            \
        const float tg = __builtin_fmaf(2.0f, rcpf(e2), -1.0f);               \
        const float ov = rcpf(e3);                                            \
        c = __builtin_fmaf(fv, c, iv * tg);                                   \
        const float ec = ex2(c * (-2.0f * L2E)) + 1.0f;                       \
        const float th = __builtin_fmaf(2.0f, rcpf(ec), -1.0f);               \
        h = ov * th;                                                          \
        /* fc dot: butterfly all-reduce over the 16-lane row (off-chain;  */  \
        /* mod-16 power-of-2 rotations reduce fully in either direction)  */  \
        float s = fcj * h;                                                    \
        s = s + dppf<ROR8>(s);                                                \
        s = s + dppf<ROR4>(s);                                                \
        s = s + dppf<ROR2>(s);                                                \
        s = s + dppf<ROR1>(s);                                                \
        if (q == 0) out[IDX] = s + fb;                                        \
    }

#pragma unroll 1
    for (int t = 0; t < SEQ; t += 2) {
        // In-loop pins: per-iteration VGPR materialization => spilling these
        // now has explicit per-iteration cost; allocator keeps them resident.
        asm volatile("" : "+v"(wr0[0]), "+v"(wr0[1]), "+v"(wr0[2]), "+v"(wr0[3]),
                          "+v"(wr0[4]), "+v"(wr0[5]), "+v"(wr0[6]), "+v"(wr0[7]),
                          "+v"(wr0[8]), "+v"(wr0[9]), "+v"(wr0[10]), "+v"(wr0[11]),
                          "+v"(wr0[12]), "+v"(wr0[13]), "+v"(wr0[14]), "+v"(wr0[15]));
        asm volatile("" : "+v"(wr1[0]), "+v"(wr1[1]), "+v"(wr1[2]), "+v"(wr1[3]),
                          "+v"(wr1[4]), "+v"(wr1[5]), "+v"(wr1[6]), "+v"(wr1[7]),
                          "+v"(wr1[8]), "+v"(wr1[9]), "+v"(wr1[10]), "+v"(wr1[11]),
                          "+v"(wr1[12]), "+v"(wr1[13]), "+v"(wr1[14]), "+v"(wr1[15]));
        asm volatile("" : "+v"(wr2[0]), "+v"(wr2[1]), "+v"(wr2[2]), "+v"(wr2[3]),
                          "+v"(wr2[4]), "+v"(wr2[5]), "+v"(wr2[6]), "+v"(wr2[7]),
                          "+v"(wr2[8]), "+v"(wr2[9]), "+v"(wr2[10]), "+v"(wr2[11]),
                          "+v"(wr2[12]), "+v"(wr2[13]), "+v"(wr2[14]), "+v"(wr2[15]));
        asm volatile("" : "+v"(wr3[0]), "+v"(wr3[1]), "+v"(wr3[2]), "+v"(wr3[3]),
                          "+v"(wr3[4]), "+v"(wr3[5]), "+v"(wr3[6]), "+v"(wr3[7]),
                          "+v"(wr3[8]), "+v"(wr3[9]), "+v"(wr3[10]), "+v"(wr3[11]),
                          "+v"(wr3[12]), "+v"(wr3[13]), "+v"(wr3[14]), "+v"(wr3[15]));
        asm volatile("" : "+v"(wi0), "+v"(wi1), "+v"(wi2), "+v"(wi3),
                          "+v"(bi0), "+v"(bi1), "+v"(bi2), "+v"(bi3),
                          "+v"(fcj), "+v"(fb));

        // depth-4 prefetch of x(t+4), x(t+5)
        const size_t ip4 = ix + 4 * (size_t)BATCH;
        const size_t ip5 = ix + 5 * (size_t)BATCH;
        const float n4 = x[(t + 4 < SEQ) ? ip4 : ix];
        const float n5 = x[(t + 5 < SEQ) ? ip5 : ix];

        BODY(x0, ix);
        BODY(x1, ix + (size_t)BATCH);

        x0 = x2; x1 = x3; x2 = n4; x3 = n5;
        ix += 2 * (size_t)BATCH;
    }
#undef BODY
#undef RSTEP_F
#undef RSTEP_B
}

extern "C" void kernel_launch(void* const* d_in, const int* in_sizes, int n_in,
                              void* d_out, int out_size, void* d_ws, size_t ws_size,
                              hipStream_t stream) {
    const float* x    = (const float*)d_in[0];
    const float* w_ih = (const float*)d_in[1];
    const float* w_hh = (const float*)d_in[2];
    const float* b_ih = (const float*)d_in[3];
    const float* b_hh = (const float*)d_in[4];
    const float* fc_w = (const float*)d_in[5];
    const float* fc_b = (const float*)d_in[6];
    float* out = (float*)d_out;

    dim3 grid(BATCH / 16);   // 256 blocks, 16 groups (elements) each
    dim3 block(256);
    lstm_scan_kernel<<<grid, block, 0, stream>>>(x, w_ih, w_hh, b_ih, b_hh,
                                                 fc_w, fc_b, out);
}